// Round 4
// baseline (2959.670 us; speedup 1.0000x reference)
//
#include <hip/hip_runtime.h>
#include <hip/hip_bf16.h>
#include <cstdint>

#define B_ 256
#define F_ 128
#define D_ 512
#define H_ 8
#define HD_ 64
#define KVAL_ 64

__device__ __forceinline__ unsigned long long f2ord64(double s) {
  unsigned long long b = (unsigned long long)__double_as_longlong(s);
  return (b & 0x8000000000000000ull) ? ~b : (b | 0x8000000000000000ull);
}

__device__ __forceinline__ float bcast(float v, int l) {
  return __uint_as_float(__builtin_amdgcn_readlane(__float_as_uint(v), l));
}

__device__ __forceinline__ double bcast64(double v, int l) {
  long long x = __double_as_longlong(v);
  unsigned lo = __builtin_amdgcn_readlane((unsigned)(x & 0xffffffffll), l);
  unsigned hi = __builtin_amdgcn_readlane((unsigned)((unsigned long long)x >> 32), l);
  return __longlong_as_double((long long)(((unsigned long long)hi << 32) | lo));
}

// ---------------------------------------------------------------------------
// pv gate in fp64 (selection-critical): means -> silu MLP -> sigmoid
// ---------------------------------------------------------------------------
__global__ __launch_bounds__(256) void pv_kernel(
    const float* __restrict__ x, const float* __restrict__ W1,
    const float* __restrict__ b1, const float* __restrict__ W2,
    const float* __restrict__ b2, double* __restrict__ pv) {
  __shared__ double comb[1024];
  __shared__ double hbuf[512];
  __shared__ double red[4];
  int b = blockIdx.x, t = threadIdx.x;
  for (int i = t; i < 1024; i += 256) {
    int d = i & 511;
    int fbase = (i < 512) ? 0 : 64;
    const float* xp = x + ((size_t)b * F_ + fbase) * D_ + d;
    double s = 0.0;
#pragma unroll 8
    for (int f = 0; f < 64; ++f) s += (double)xp[(size_t)f * D_];
    comb[i] = s * (1.0 / 64.0);
  }
  __syncthreads();
  for (int j = t; j < 512; j += 256) {
    double acc = (double)b1[j];
#pragma unroll 4
    for (int i = 0; i < 1024; ++i) acc += comb[i] * (double)W1[i * 512 + j];
    hbuf[j] = acc / (1.0 + exp(-acc));  // silu
  }
  __syncthreads();
  double part = 0.0;
  for (int j = t; j < 512; j += 256) part += hbuf[j] * (double)W2[j];
  for (int off = 32; off; off >>= 1) part += __shfl_xor(part, off);
  int lane = t & 63, w = t >> 6;
  if (lane == 0) red[w] = part;
  __syncthreads();
  if (t == 0) {
    double tot = red[0] + red[1] + red[2] + red[3] + (double)b2[0];
    pv[b] = 1.0 / (1.0 + exp(-tot));
  }
}

// ---------------------------------------------------------------------------
// pack [Wq|Wk] -> fp64 Wqk (512 x 1024), [bq|bk] -> fp64 bqk (1024)
// ---------------------------------------------------------------------------
__global__ __launch_bounds__(256) void pack_f64_kernel(
    const float* __restrict__ Wq, const float* __restrict__ Wk,
    const float* __restrict__ bq, const float* __restrict__ bk,
    double* __restrict__ Wqk, double* __restrict__ bqk) {
  int idx = blockIdx.x * 256 + threadIdx.x;
  if (idx < 512 * 1024) {
    int k = idx >> 10, n = idx & 1023;
    float v = (n < 512) ? Wq[k * 512 + n] : Wk[k * 512 + (n - 512)];
    Wqk[idx] = (double)v;
  }
  if (idx < 1024) {
    bqk[idx] = (double)((idx < 512) ? bq[idx] : bk[idx - 512]);
  }
}

// ---------------------------------------------------------------------------
// fp64 GEMM: C[M,N](f64) = A[M,K](f32 cast) @ Bw[K,N](f64) + bias(f64)
// 64x64 tile, BK=16, 256 threads, 4x4 acc
// ---------------------------------------------------------------------------
__global__ __launch_bounds__(256) void gemm_f64_kernel(
    const float* __restrict__ A, const double* __restrict__ Bw,
    const double* __restrict__ bias, double* __restrict__ C,
    int M, int N, int K) {
  __shared__ double As[16][68];
  __shared__ double Bs[16][68];
  int t = threadIdx.x;
  int tx = t & 15, ty = t >> 4;
  int m0 = blockIdx.y * 64, n0 = blockIdx.x * 64;
  int am = t >> 2, ak = (t & 3) * 4;
  int bn = t & 63, bk0 = t >> 6;
  const float* Ap = A + (size_t)(m0 + am) * K + ak;
  const double* Bp = Bw + (size_t)bk0 * N + n0 + bn;
  double acc[4][4] = {};
  for (int k0 = 0; k0 < K; k0 += 16) {
    float4 av = *(const float4*)(Ap + k0);
    As[ak + 0][am] = (double)av.x;
    As[ak + 1][am] = (double)av.y;
    As[ak + 2][am] = (double)av.z;
    As[ak + 3][am] = (double)av.w;
#pragma unroll
    for (int kk = 0; kk < 4; ++kk)
      Bs[bk0 + kk * 4][bn] = Bp[(size_t)(k0 + kk * 4) * N];
    __syncthreads();
#pragma unroll
    for (int k = 0; k < 16; ++k) {
      double a0 = As[k][ty * 4 + 0], a1 = As[k][ty * 4 + 1];
      double a2 = As[k][ty * 4 + 2], a3 = As[k][ty * 4 + 3];
      double b0 = Bs[k][tx * 4 + 0], b1 = Bs[k][tx * 4 + 1];
      double b2 = Bs[k][tx * 4 + 2], b3 = Bs[k][tx * 4 + 3];
      acc[0][0] += a0 * b0; acc[0][1] += a0 * b1; acc[0][2] += a0 * b2; acc[0][3] += a0 * b3;
      acc[1][0] += a1 * b0; acc[1][1] += a1 * b1; acc[1][2] += a1 * b2; acc[1][3] += a1 * b3;
      acc[2][0] += a2 * b0; acc[2][1] += a2 * b1; acc[2][2] += a2 * b2; acc[2][3] += a2 * b3;
      acc[3][0] += a3 * b0; acc[3][1] += a3 * b1; acc[3][2] += a3 * b2; acc[3][3] += a3 * b3;
    }
    __syncthreads();
  }
#pragma unroll
  for (int i = 0; i < 4; ++i) {
#pragma unroll
    for (int j = 0; j < 4; ++j)
      C[(size_t)(m0 + ty * 4 + i) * N + n0 + tx * 4 + j] =
          acc[i][j] + bias[n0 + tx * 4 + j];
  }
}

// ---------------------------------------------------------------------------
// fp32 tiled GEMM: C[M,N] = A[M,K] @ B[K,N] + bias[N]  (for v and out proj)
// ---------------------------------------------------------------------------
__global__ __launch_bounds__(256) void gemm_bias_kernel(
    const float* __restrict__ A, const float* __restrict__ Bw,
    const float* __restrict__ bias, float* __restrict__ C,
    int M, int N, int K) {
  __shared__ float As[16][68];
  __shared__ float Bs[16][68];
  int t = threadIdx.x;
  int tx = t & 15, ty = t >> 4;
  int m0 = blockIdx.y * 64, n0 = blockIdx.x * 64;
  int am = t >> 2, ak = (t & 3) * 4;
  int bn = t & 63, bk0 = t >> 6;
  const float* Ap = A + (size_t)(m0 + am) * K + ak;
  const float* Bp = Bw + (size_t)bk0 * N + n0 + bn;
  float acc[4][4] = {};
  for (int k0 = 0; k0 < K; k0 += 16) {
    float4 av = *(const float4*)(Ap + k0);
    As[ak + 0][am] = av.x;
    As[ak + 1][am] = av.y;
    As[ak + 2][am] = av.z;
    As[ak + 3][am] = av.w;
#pragma unroll
    for (int kk = 0; kk < 4; ++kk)
      Bs[bk0 + kk * 4][bn] = Bp[(size_t)(k0 + kk * 4) * N];
    __syncthreads();
#pragma unroll
    for (int k = 0; k < 16; ++k) {
      float4 a = *(const float4*)&As[k][ty * 4];
      float4 b = *(const float4*)&Bs[k][tx * 4];
      acc[0][0] += a.x * b.x; acc[0][1] += a.x * b.y;
      acc[0][2] += a.x * b.z; acc[0][3] += a.x * b.w;
      acc[1][0] += a.y * b.x; acc[1][1] += a.y * b.y;
      acc[1][2] += a.y * b.z; acc[1][3] += a.y * b.w;
      acc[2][0] += a.z * b.x; acc[2][1] += a.z * b.y;
      acc[2][2] += a.z * b.z; acc[2][3] += a.z * b.w;
      acc[3][0] += a.w * b.x; acc[3][1] += a.w * b.y;
      acc[3][2] += a.w * b.z; acc[3][3] += a.w * b.w;
    }
    __syncthreads();
  }
  float4 bias4 = *(const float4*)&bias[n0 + tx * 4];
#pragma unroll
  for (int i = 0; i < 4; ++i) {
    float4 o;
    o.x = acc[i][0] + bias4.x;
    o.y = acc[i][1] + bias4.y;
    o.z = acc[i][2] + bias4.z;
    o.w = acc[i][3] + bias4.w;
    *(float4*)&C[(size_t)(m0 + ty * 4 + i) * N + n0 + tx * 4] = o;
  }
}

// ---------------------------------------------------------------------------
// attention: block per (b,h). fp64 scores; exact top-64 via 64-bit radix
// select, then a symmetric soft ramp of half-width EPS centered between the
// 64th and 65th scores: W(s)=clamp(0.5+(s-mid)/(2*EPS),0,1). For gap>2*EPS
// this is bit-identical to the hard cut; near-ties (where the fp32 reference's
// own rounding decides the winner) get ~half weight each, halving the flip
// error. Softmax + PV in fp32.
// ---------------------------------------------------------------------------
__global__ __launch_bounds__(256) void attn_kernel(
    const double* __restrict__ qk, const float* __restrict__ vbuf,
    const float* __restrict__ corr_prior, const float* __restrict__ feat_imp,
    const double* __restrict__ pv, float* __restrict__ attn_out, int b_off) {
  __shared__ double kT[64][128];  // k[f][d] at kT[d][(f+d)&127]
  int bh = blockIdx.x;
  int b = bh >> 3, h = bh & 7;  // chunk-local b
  int t = threadIdx.x, lane = t & 63, w = t >> 6;
  for (int n = 0; n < 32; ++n) {
    int f = w + 4 * n;
    kT[lane][(f + lane) & 127] =
        qk[((size_t)(b * F_ + f)) * 1024 + 512 + h * 64 + lane];
  }
  __syncthreads();
  double pvb = pv[b_off + b] * 0.5;
  double fiA = (double)feat_imp[lane];       // column j0 = lane
  double fiB = (double)feat_imp[64 + lane];  // column j1 = lane+64
  const double SLOPE = 2.5e5;  // 1/(2*EPS), EPS = 2e-6
  for (int f = w; f < F_; f += 4) {
    double qreg = qk[((size_t)(b * F_ + f)) * 1024 + h * 64 + lane];
    double s0 = 0.0, s1 = 0.0;
#pragma unroll 8
    for (int d = 0; d < 64; ++d) {
      double qd = bcast64(qreg, d);
      s0 += qd * kT[d][(lane + d) & 127];
      s1 += qd * kT[d][(lane + 64 + d) & 127];
    }
    double fif = (double)feat_imp[f];
    double cp0 = (double)corr_prior[f * 128 + lane] * fif * fiA;
    double cp1 = (double)corr_prior[f * 128 + 64 + lane] * fif * fiB;
    double add0 = (f < 64) ? 0.0 : pvb;  // XOR mask, j0 < 64
    double add1 = (f < 64) ? pvb : 0.0;  // j1 >= 64
    s0 = s0 * 0.125 + cp0 + add0;
    s1 = s1 * 0.125 + cp1 + add1;
    // exact 64th-largest of 128 on ordered-uint64 keys
    unsigned long long u0 = f2ord64(s0), u1 = f2ord64(s1), T = 0ull;
    for (int bit = 63; bit >= 0; --bit) {
      unsigned long long cand = T | (1ull << bit);
      int c = __popcll(__ballot(u0 >= cand)) + __popcll(__ballot(u1 >= cand));
      if (c >= KVAL_) T = cand;
    }
    // s64 = score at T; s65 = largest score strictly below T
    double sT = -1e300, sU = -1e300;
    if (u0 == T) sT = s0;
    if (u1 == T && s1 > sT) sT = s1;
    if (u0 < T) sU = s0;
    if (u1 < T && s1 > sU) sU = s1;
    for (int off = 32; off; off >>= 1) {
      sT = fmax(sT, __shfl_xor(sT, off));
      sU = fmax(sU, __shfl_xor(sU, off));
    }
    double mid = 0.5 * (sT + sU);
    double W0 = fmin(1.0, fmax(0.0, 0.5 + (s0 - mid) * SLOPE));
    double W1v = fmin(1.0, fmax(0.0, 0.5 + (s1 - mid) * SLOPE));
    // softmax max over elements with any weight (global max has W=1)
    double mm = fmax(s0, s1);
    for (int off = 32; off; off >>= 1) mm = fmax(mm, __shfl_xor(mm, off));
    float p0 = (float)W0 * expf((float)(s0 - mm));
    float p1 = (float)W1v * expf((float)(s1 - mm));
    float zz = p0 + p1;
    for (int off = 32; off; off >>= 1) zz += __shfl_xor(zz, off);
    float inv = 1.f / zz;
    const float* vb = vbuf + ((size_t)b * F_) * 512 + h * 64 + lane;
    float o = 0.f;
#pragma unroll 8
    for (int j = 0; j < 64; ++j) o += bcast(p0, j) * vb[(size_t)j * 512];
#pragma unroll 8
    for (int j = 0; j < 64; ++j) o += bcast(p1, j) * vb[(size_t)(j + 64) * 512];
    attn_out[((size_t)(b * F_ + f)) * 512 + h * 64 + lane] = o * inv;
  }
}

extern "C" void kernel_launch(void* const* d_in, const int* in_sizes, int n_in,
                              void* d_out, int out_size, void* d_ws,
                              size_t ws_size, hipStream_t stream) {
  const float* x = (const float*)d_in[0];
  const float* Wq = (const float*)d_in[1];
  const float* bq = (const float*)d_in[2];
  const float* Wk = (const float*)d_in[3];
  const float* bk = (const float*)d_in[4];
  const float* Wv = (const float*)d_in[5];
  const float* bv = (const float*)d_in[6];
  const float* Wo = (const float*)d_in[7];
  const float* bo = (const float*)d_in[8];
  const float* corr = (const float*)d_in[9];
  const float* fimp = (const float*)d_in[10];
  const float* W1 = (const float*)d_in[11];
  const float* b1 = (const float*)d_in[12];
  const float* W2 = (const float*)d_in[13];
  const float* b2 = (const float*)d_in[14];
  float* out = (float*)d_out;
  float* ws = (float*)d_ws;

  // workspace head (floats, 8B-aligned offsets):
  //   pv_hi   : 256 doubles  @ 0        (512 floats)
  //   bqk_hi  : 1024 doubles @ 512      (2048 floats)
  //   Wqk_hi  : 512*1024 dbl @ 2560     (1048576 floats)
  double* pv_hi = (double*)ws;
  double* bqk_hi = (double*)(ws + 512);
  double* Wqk_hi = (double*)(ws + 2560);
  const size_t head = 2560 + 1048576;  // = 1,051,136 floats (~4.2 MB)
  size_t ws_floats = ws_size / 4;

  // per chunk of Bc batches:
  //   qk_hi: Bc*128*1024 doubles = Bc*262144 floats
  //   vbuf : Bc*128*512  floats  = Bc*65536
  //   attnb: Bc*128*512  floats  = Bc*65536
  int Bc = 1;
  for (int cand = 256; cand >= 1; cand >>= 1) {
    if (head + (size_t)cand * 393216 <= ws_floats) { Bc = cand; break; }
  }
  double* qk_hi = (double*)(ws + head);
  float* vbuf = ws + head + (size_t)Bc * 262144;
  float* attnb = vbuf + (size_t)Bc * 65536;

  hipLaunchKernelGGL(pv_kernel, dim3(B_), dim3(256), 0, stream,
                     x, W1, b1, W2, b2, pv_hi);
  hipLaunchKernelGGL(pack_f64_kernel, dim3(2048), dim3(256), 0, stream,
                     Wq, Wk, bq, bk, Wqk_hi, bqk_hi);

  for (int b0 = 0; b0 < B_; b0 += Bc) {
    const float* xc = x + (size_t)b0 * F_ * D_;
    float* outc = out + (size_t)b0 * F_ * D_;
    int Mc = Bc * F_;
    hipLaunchKernelGGL(gemm_f64_kernel, dim3(16, Mc / 64), dim3(256), 0,
                       stream, xc, Wqk_hi, bqk_hi, qk_hi, Mc, 1024, 512);
    hipLaunchKernelGGL(gemm_bias_kernel, dim3(8, Mc / 64), dim3(256), 0,
                       stream, xc, Wv, bv, vbuf, Mc, 512, 512);
    hipLaunchKernelGGL(attn_kernel, dim3(Bc * H_), dim3(256), 0, stream,
                       qk_hi, vbuf, corr, fimp, pv_hi, attnb, b0);
    hipLaunchKernelGGL(gemm_bias_kernel, dim3(8, Mc / 64), dim3(256), 0,
                       stream, attnb, Wo, bo, outc, Mc, 512, 512);
  }
}

// Round 5
// 2780.525 us; speedup vs baseline: 1.0644x; 1.0644x over previous
//
#include <hip/hip_runtime.h>
#include <hip/hip_bf16.h>
#include <cstdint>

#define B_ 256
#define F_ 128
#define D_ 512
#define H_ 8
#define KVAL_ 64

typedef unsigned short ushort_t;
typedef __attribute__((ext_vector_type(8))) short short8;
typedef __attribute__((ext_vector_type(4))) float floatx4;

__device__ __forceinline__ unsigned long long f2ord64(double s) {
  unsigned long long b = (unsigned long long)__double_as_longlong(s);
  return (b & 0x8000000000000000ull) ? ~b : (b | 0x8000000000000000ull);
}

__device__ __forceinline__ float bcast(float v, int l) {
  return __uint_as_float(__builtin_amdgcn_readlane(__float_as_uint(v), l));
}

__device__ __forceinline__ double bcast64(double v, int l) {
  long long x = __double_as_longlong(v);
  unsigned lo = __builtin_amdgcn_readlane((unsigned)(x & 0xffffffffll), l);
  unsigned hi = __builtin_amdgcn_readlane((unsigned)((unsigned long long)x >> 32), l);
  return __longlong_as_double((long long)(((unsigned long long)hi << 32) | lo));
}

__device__ __forceinline__ ushort_t f2bf(float f) {
  __hip_bfloat16 h = __float2bfloat16(f);
  return *reinterpret_cast<ushort_t*>(&h);
}
__device__ __forceinline__ float bf2f(ushort_t u) {
  __hip_bfloat16 h = *reinterpret_cast<__hip_bfloat16*>(&u);
  return __bfloat162float(h);
}

// ---------------------------------------------------------------------------
// pv gate in fp64 (selection-critical): means -> silu MLP -> sigmoid
// ---------------------------------------------------------------------------
__global__ __launch_bounds__(256) void pv_kernel(
    const float* __restrict__ x, const float* __restrict__ W1,
    const float* __restrict__ b1, const float* __restrict__ W2,
    const float* __restrict__ b2, double* __restrict__ pv) {
  __shared__ double comb[1024];
  __shared__ double hbuf[512];
  __shared__ double red[4];
  int b = blockIdx.x, t = threadIdx.x;
  for (int i = t; i < 1024; i += 256) {
    int d = i & 511;
    int fbase = (i < 512) ? 0 : 64;
    const float* xp = x + ((size_t)b * F_ + fbase) * D_ + d;
    double s = 0.0;
#pragma unroll 8
    for (int f = 0; f < 64; ++f) s += (double)xp[(size_t)f * D_];
    comb[i] = s * (1.0 / 64.0);
  }
  __syncthreads();
  for (int j = t; j < 512; j += 256) {
    double acc = (double)b1[j];
#pragma unroll 4
    for (int i = 0; i < 1024; ++i) acc += comb[i] * (double)W1[i * 512 + j];
    hbuf[j] = acc / (1.0 + exp(-acc));  // silu
  }
  __syncthreads();
  double part = 0.0;
  for (int j = t; j < 512; j += 256) part += hbuf[j] * (double)W2[j];
  for (int off = 32; off; off >>= 1) part += __shfl_xor(part, off);
  int lane = t & 63, w = t >> 6;
  if (lane == 0) red[w] = part;
  __syncthreads();
  if (t == 0) {
    double tot = red[0] + red[1] + red[2] + red[3] + (double)b2[0];
    pv[b] = 1.0 / (1.0 + exp(-tot));
  }
}

// ---------------------------------------------------------------------------
// pack [Wq|Wk] -> fp64 Wqk (512 x 1024), [bq|bk] -> fp64 bqk (1024)
// ---------------------------------------------------------------------------
__global__ __launch_bounds__(256) void pack_f64_kernel(
    const float* __restrict__ Wq, const float* __restrict__ Wk,
    const float* __restrict__ bq, const float* __restrict__ bk,
    double* __restrict__ Wqk, double* __restrict__ bqk) {
  int idx = blockIdx.x * 256 + threadIdx.x;
  if (idx < 512 * 1024) {
    int k = idx >> 10, n = idx & 1023;
    float v = (n < 512) ? Wq[k * 512 + n] : Wk[k * 512 + (n - 512)];
    Wqk[idx] = (double)v;
  }
  if (idx < 1024) {
    bqk[idx] = (double)((idx < 512) ? bq[idx] : bk[idx - 512]);
  }
}

// ---------------------------------------------------------------------------
// pack W (512x512 fp32, [k][n]) -> WT hi/lo bf16 [n][k] split
// grid 1024 x 256: i -> n = i>>9 (slow), k = i&511 (fast) => coalesced writes
// ---------------------------------------------------------------------------
__global__ __launch_bounds__(256) void pack_wt_kernel(
    const float* __restrict__ W, ushort_t* __restrict__ hiT,
    ushort_t* __restrict__ loT) {
  int i = blockIdx.x * 256 + threadIdx.x;
  int n = i >> 9, k = i & 511;
  float v = W[(size_t)k * 512 + n];  // gather read, L1/L2-cached (1MB src)
  ushort_t h = f2bf(v);
  hiT[i] = h;
  loT[i] = f2bf(v - bf2f(h));
}

// ---------------------------------------------------------------------------
// split-bf16 MFMA GEMM: C[M,512] = A[M,512](fp32) @ (Whi+Wlo) + bias
// computed as Ahi@Whi + Ahi@Wlo + Alo@Whi over virtual K=1536 (3 segments),
// A split into hi/lo bf16 on the fly during staging. W given transposed
// [n][k] bf16 so both operands are K-contiguous. 128x128 tile, BK=32,
// 4 waves in 2x2, 16x16x32 MFMA, LDS rows padded to 40 bf16 (<=2-way banks).
// ---------------------------------------------------------------------------
__global__ __launch_bounds__(256) void mfma_gemm_split(
    const float* __restrict__ A, const ushort_t* __restrict__ WhiT,
    const ushort_t* __restrict__ WloT, const float* __restrict__ bias,
    float* __restrict__ C) {
  __shared__ ushort_t As[128 * 40];
  __shared__ ushort_t Bs[128 * 40];
  int t = threadIdx.x;
  int lane = t & 63, w = t >> 6;
  int wm = w >> 1, wn = w & 1;
  int mrow = lane & 15, quad = lane >> 4;
  int m0 = blockIdx.y * 128, n0 = blockIdx.x * 128;
  floatx4 acc[4][4] = {};
  for (int kt = 0; kt < 48; ++kt) {
    int seg = kt >> 4;
    int k0 = (kt & 15) * 32;
    const ushort_t* Bseg = (seg == 1) ? WloT : WhiT;
    bool lo = (seg == 2);
    __syncthreads();
#pragma unroll
    for (int p = 0; p < 2; ++p) {
      int idx = p * 256 + t;
      int r = idx >> 2, c = idx & 3;
      const float* ap = A + (size_t)(m0 + r) * 512 + k0 + c * 8;
      floatx4 f0 = *(const floatx4*)ap;
      floatx4 f1 = *(const floatx4*)(ap + 4);
      short8 av;
#pragma unroll
      for (int j = 0; j < 8; ++j) {
        float fv = (j < 4) ? f0[j] : f1[j - 4];
        ushort_t hb = f2bf(fv);
        ushort_t ob = lo ? f2bf(fv - bf2f(hb)) : hb;
        av[j] = (short)ob;
      }
      *(short8*)&As[r * 40 + c * 8] = av;
      *(short8*)&Bs[r * 40 + c * 8] =
          *(const short8*)(Bseg + (size_t)(n0 + r) * 512 + k0 + c * 8);
    }
    __syncthreads();
    short8 af[4], bf8[4];
    int abase = (wm * 64 + mrow) * 40 + quad * 8;
    int bbase = (wn * 64 + mrow) * 40 + quad * 8;
#pragma unroll
    for (int i = 0; i < 4; ++i) {
      af[i] = *(const short8*)&As[abase + i * 640];
      bf8[i] = *(const short8*)&Bs[bbase + i * 640];
    }
#pragma unroll
    for (int mt = 0; mt < 4; ++mt)
#pragma unroll
      for (int nt = 0; nt < 4; ++nt)
        acc[mt][nt] = __builtin_amdgcn_mfma_f32_16x16x32_bf16(
            af[mt], bf8[nt], acc[mt][nt], 0, 0, 0);
  }
#pragma unroll
  for (int nt = 0; nt < 4; ++nt) {
    int gn = n0 + wn * 64 + nt * 16 + mrow;
    float bb = bias[gn];
#pragma unroll
    for (int mt = 0; mt < 4; ++mt) {
      int gm = m0 + wm * 64 + mt * 16 + quad * 4;
#pragma unroll
      for (int rg = 0; rg < 4; ++rg)
        C[(size_t)(gm + rg) * 512 + gn] = acc[mt][nt][rg] + bb;
    }
  }
}

// ---------------------------------------------------------------------------
// fp64 GEMM: C[M,N](f64) = A[M,K](f32 cast) @ Bw[K,N](f64) + bias(f64)
// 64x64 tile, BK=16, 256 threads, 4x4 acc  (unchanged from round 4)
// ---------------------------------------------------------------------------
__global__ __launch_bounds__(256) void gemm_f64_kernel(
    const float* __restrict__ A, const double* __restrict__ Bw,
    const double* __restrict__ bias, double* __restrict__ C,
    int M, int N, int K) {
  __shared__ double As[16][68];
  __shared__ double Bs[16][68];
  int t = threadIdx.x;
  int tx = t & 15, ty = t >> 4;
  int m0 = blockIdx.y * 64, n0 = blockIdx.x * 64;
  int am = t >> 2, ak = (t & 3) * 4;
  int bn = t & 63, bk0 = t >> 6;
  const float* Ap = A + (size_t)(m0 + am) * K + ak;
  const double* Bp = Bw + (size_t)bk0 * N + n0 + bn;
  double acc[4][4] = {};
  for (int k0 = 0; k0 < K; k0 += 16) {
    float4 av = *(const float4*)(Ap + k0);
    As[ak + 0][am] = (double)av.x;
    As[ak + 1][am] = (double)av.y;
    As[ak + 2][am] = (double)av.z;
    As[ak + 3][am] = (double)av.w;
#pragma unroll
    for (int kk = 0; kk < 4; ++kk)
      Bs[bk0 + kk * 4][bn] = Bp[(size_t)(k0 + kk * 4) * N];
    __syncthreads();
#pragma unroll
    for (int k = 0; k < 16; ++k) {
      double a0 = As[k][ty * 4 + 0], a1 = As[k][ty * 4 + 1];
      double a2 = As[k][ty * 4 + 2], a3 = As[k][ty * 4 + 3];
      double b0 = Bs[k][tx * 4 + 0], b1 = Bs[k][tx * 4 + 1];
      double b2 = Bs[k][tx * 4 + 2], b3 = Bs[k][tx * 4 + 3];
      acc[0][0] += a0 * b0; acc[0][1] += a0 * b1; acc[0][2] += a0 * b2; acc[0][3] += a0 * b3;
      acc[1][0] += a1 * b0; acc[1][1] += a1 * b1; acc[1][2] += a1 * b2; acc[1][3] += a1 * b3;
      acc[2][0] += a2 * b0; acc[2][1] += a2 * b1; acc[2][2] += a2 * b2; acc[2][3] += a2 * b3;
      acc[3][0] += a3 * b0; acc[3][1] += a3 * b1; acc[3][2] += a3 * b2; acc[3][3] += a3 * b3;
    }
    __syncthreads();
  }
#pragma unroll
  for (int i = 0; i < 4; ++i) {
#pragma unroll
    for (int j = 0; j < 4; ++j)
      C[(size_t)(m0 + ty * 4 + i) * N + n0 + tx * 4 + j] =
          acc[i][j] + bias[n0 + tx * 4 + j];
  }
}

// ---------------------------------------------------------------------------
// attention (unchanged math from round 4, verified): fp64 scores, exact
// radix select + soft ramp (EPS=2e-6), softmax+PV fp32.
// ---------------------------------------------------------------------------
__global__ __launch_bounds__(256) void attn_kernel(
    const double* __restrict__ qk, const float* __restrict__ vbuf,
    const float* __restrict__ corr_prior, const float* __restrict__ feat_imp,
    const double* __restrict__ pv, float* __restrict__ attn_out, int b_off) {
  __shared__ double kT[64][128];  // k[f][d] at kT[d][(f+d)&127]
  int bh = blockIdx.x;
  int b = bh >> 3, h = bh & 7;  // chunk-local b
  int t = threadIdx.x, lane = t & 63, w = t >> 6;
  for (int n = 0; n < 32; ++n) {
    int f = w + 4 * n;
    kT[lane][(f + lane) & 127] =
        qk[((size_t)(b * F_ + f)) * 1024 + 512 + h * 64 + lane];
  }
  __syncthreads();
  double pvb = pv[b_off + b] * 0.5;
  double fiA = (double)feat_imp[lane];
  double fiB = (double)feat_imp[64 + lane];
  const double SLOPE = 2.5e5;  // 1/(2*EPS), EPS = 2e-6
  for (int f = w; f < F_; f += 4) {
    double qreg = qk[((size_t)(b * F_ + f)) * 1024 + h * 64 + lane];
    double s0 = 0.0, s1 = 0.0;
#pragma unroll 8
    for (int d = 0; d < 64; ++d) {
      double qd = bcast64(qreg, d);
      s0 += qd * kT[d][(lane + d) & 127];
      s1 += qd * kT[d][(lane + 64 + d) & 127];
    }
    double fif = (double)feat_imp[f];
    double cp0 = (double)corr_prior[f * 128 + lane] * fif * fiA;
    double cp1 = (double)corr_prior[f * 128 + 64 + lane] * fif * fiB;
    double add0 = (f < 64) ? 0.0 : pvb;
    double add1 = (f < 64) ? pvb : 0.0;
    s0 = s0 * 0.125 + cp0 + add0;
    s1 = s1 * 0.125 + cp1 + add1;
    unsigned long long u0 = f2ord64(s0), u1 = f2ord64(s1), T = 0ull;
    for (int bit = 63; bit >= 0; --bit) {
      unsigned long long cand = T | (1ull << bit);
      int c = __popcll(__ballot(u0 >= cand)) + __popcll(__ballot(u1 >= cand));
      if (c >= KVAL_) T = cand;
    }
    double sT = -1e300, sU = -1e300;
    if (u0 == T) sT = s0;
    if (u1 == T && s1 > sT) sT = s1;
    if (u0 < T) sU = s0;
    if (u1 < T && s1 > sU) sU = s1;
    for (int off = 32; off; off >>= 1) {
      sT = fmax(sT, __shfl_xor(sT, off));
      sU = fmax(sU, __shfl_xor(sU, off));
    }
    double mid = 0.5 * (sT + sU);
    double W0 = fmin(1.0, fmax(0.0, 0.5 + (s0 - mid) * SLOPE));
    double W1v = fmin(1.0, fmax(0.0, 0.5 + (s1 - mid) * SLOPE));
    double mm = fmax(s0, s1);
    for (int off = 32; off; off >>= 1) mm = fmax(mm, __shfl_xor(mm, off));
    float p0 = (float)W0 * expf((float)(s0 - mm));
    float p1 = (float)W1v * expf((float)(s1 - mm));
    float zz = p0 + p1;
    for (int off = 32; off; off >>= 1) zz += __shfl_xor(zz, off);
    float inv = 1.f / zz;
    const float* vb = vbuf + ((size_t)b * F_) * 512 + h * 64 + lane;
    float o = 0.f;
#pragma unroll 8
    for (int j = 0; j < 64; ++j) o += bcast(p0, j) * vb[(size_t)j * 512];
#pragma unroll 8
    for (int j = 0; j < 64; ++j) o += bcast(p1, j) * vb[(size_t)(j + 64) * 512];
    attn_out[((size_t)(b * F_ + f)) * 512 + h * 64 + lane] = o * inv;
  }
}

extern "C" void kernel_launch(void* const* d_in, const int* in_sizes, int n_in,
                              void* d_out, int out_size, void* d_ws,
                              size_t ws_size, hipStream_t stream) {
  const float* x = (const float*)d_in[0];
  const float* Wq = (const float*)d_in[1];
  const float* bq = (const float*)d_in[2];
  const float* Wk = (const float*)d_in[3];
  const float* bk = (const float*)d_in[4];
  const float* Wv = (const float*)d_in[5];
  const float* bv = (const float*)d_in[6];
  const float* Wo = (const float*)d_in[7];
  const float* bo = (const float*)d_in[8];
  const float* corr = (const float*)d_in[9];
  const float* fimp = (const float*)d_in[10];
  const float* W1 = (const float*)d_in[11];
  const float* b1 = (const float*)d_in[12];
  const float* W2 = (const float*)d_in[13];
  const float* b2 = (const float*)d_in[14];
  float* out = (float*)d_out;
  float* ws = (float*)d_ws;

  // workspace layout (float units):
  //   pv_hi  @0        512      (256 f64)
  //   bqk_hi @512      2048     (1024 f64)
  //   Wqk_hi @2560     1048576  (512*1024 f64)
  //   WvhiT  @1051136  131072   (512*512 bf16)
  //   WvloT  @1182208  131072
  //   WohiT  @1313280  131072
  //   WoloT  @1444352  131072
  //   vbuf   @1575424  16777216 (32768*512 f32)
  //   attnb  @18352640 16777216
  //   qk     @35129856 Bc*262144 (Bc*128*1024 f64, chunk-adaptive)
  double* pv_hi = (double*)ws;
  double* bqk_hi = (double*)(ws + 512);
  double* Wqk_hi = (double*)(ws + 2560);
  ushort_t* WvhiT = (ushort_t*)(ws + 1051136);
  ushort_t* WvloT = (ushort_t*)(ws + 1182208);
  ushort_t* WohiT = (ushort_t*)(ws + 1313280);
  ushort_t* WoloT = (ushort_t*)(ws + 1444352);
  float* vbuf = ws + 1575424;
  float* attnb = ws + 18352640;
  double* qk = (double*)(ws + 35129856);
  const size_t head = 35129856;
  size_t ws_floats = ws_size / 4;
  int Bc = 8;
  for (int cand = 256; cand >= 8; cand >>= 1)
    if (head + (size_t)cand * 262144 <= ws_floats) { Bc = cand; break; }

  hipLaunchKernelGGL(pv_kernel, dim3(B_), dim3(256), 0, stream,
                     x, W1, b1, W2, b2, pv_hi);
  hipLaunchKernelGGL(pack_f64_kernel, dim3(2048), dim3(256), 0, stream,
                     Wq, Wk, bq, bk, Wqk_hi, bqk_hi);
  hipLaunchKernelGGL(pack_wt_kernel, dim3(1024), dim3(256), 0, stream,
                     Wv, WvhiT, WvloT);
  hipLaunchKernelGGL(pack_wt_kernel, dim3(1024), dim3(256), 0, stream,
                     Wo, WohiT, WoloT);
  // v projection: full batch, M = 32768
  hipLaunchKernelGGL(mfma_gemm_split, dim3(4, 256), dim3(256), 0, stream,
                     x, WvhiT, WvloT, bv, vbuf);
  // selection path, chunked over batch
  for (int b0 = 0; b0 < B_; b0 += Bc) {
    hipLaunchKernelGGL(gemm_f64_kernel, dim3(16, Bc * 2), dim3(256), 0, stream,
                       x + (size_t)b0 * 65536, Wqk_hi, bqk_hi, qk,
                       Bc * 128, 1024, 512);
    hipLaunchKernelGGL(attn_kernel, dim3(Bc * 8), dim3(256), 0, stream,
                       qk, vbuf + (size_t)b0 * 65536, corr, fimp, pv_hi,
                       attnb + (size_t)b0 * 65536, b0);
  }
  // output projection: full batch
  hipLaunchKernelGGL(mfma_gemm_split, dim3(4, 256), dim3(256), 0, stream,
                     attnb, WohiT, WoloT, bo, out);
}

// Round 6
// 1977.020 us; speedup vs baseline: 1.4970x; 1.4064x over previous
//
#include <hip/hip_runtime.h>
#include <hip/hip_bf16.h>
#include <cstdint>

#define B_ 256
#define F_ 128
#define D_ 512
#define H_ 8
#define KVAL_ 64

typedef unsigned short ushort_t;
typedef __attribute__((ext_vector_type(8))) short short8;
typedef __attribute__((ext_vector_type(4))) float floatx4;

__device__ __forceinline__ unsigned f2ord32(float f) {
  unsigned b = __float_as_uint(f);
  return (b & 0x80000000u) ? ~b : (b | 0x80000000u);
}

__device__ __forceinline__ unsigned long long f2ord64(double s) {
  unsigned long long b = (unsigned long long)__double_as_longlong(s);
  return (b & 0x8000000000000000ull) ? ~b : (b | 0x8000000000000000ull);
}

__device__ __forceinline__ float bcast(float v, int l) {
  return __uint_as_float(__builtin_amdgcn_readlane(__float_as_uint(v), l));
}

__device__ __forceinline__ double bcast64(double v, int l) {
  long long x = __double_as_longlong(v);
  unsigned lo = __builtin_amdgcn_readlane((unsigned)(x & 0xffffffffll), l);
  unsigned hi = __builtin_amdgcn_readlane((unsigned)((unsigned long long)x >> 32), l);
  return __longlong_as_double((long long)(((unsigned long long)hi << 32) | lo));
}

__device__ __forceinline__ ushort_t f2bf(float f) {
  __hip_bfloat16 h = __float2bfloat16(f);
  return *reinterpret_cast<ushort_t*>(&h);
}
__device__ __forceinline__ float bf2f(ushort_t u) {
  __hip_bfloat16 h = *reinterpret_cast<__hip_bfloat16*>(&u);
  return __bfloat162float(h);
}

// ---------------------------------------------------------------------------
// pv gate in fp64 (selection-critical): means -> silu MLP -> sigmoid
// ---------------------------------------------------------------------------
__global__ __launch_bounds__(256) void pv_kernel(
    const float* __restrict__ x, const float* __restrict__ W1,
    const float* __restrict__ b1, const float* __restrict__ W2,
    const float* __restrict__ b2, double* __restrict__ pv) {
  __shared__ double comb[1024];
  __shared__ double hbuf[512];
  __shared__ double red[4];
  int b = blockIdx.x, t = threadIdx.x;
  for (int i = t; i < 1024; i += 256) {
    int d = i & 511;
    int fbase = (i < 512) ? 0 : 64;
    const float* xp = x + ((size_t)b * F_ + fbase) * D_ + d;
    double s = 0.0;
#pragma unroll 8
    for (int f = 0; f < 64; ++f) s += (double)xp[(size_t)f * D_];
    comb[i] = s * (1.0 / 64.0);
  }
  __syncthreads();
  for (int j = t; j < 512; j += 256) {
    double acc = (double)b1[j];
#pragma unroll 4
    for (int i = 0; i < 1024; ++i) acc += comb[i] * (double)W1[i * 512 + j];
    hbuf[j] = acc / (1.0 + exp(-acc));  // silu
  }
  __syncthreads();
  double part = 0.0;
  for (int j = t; j < 512; j += 256) part += hbuf[j] * (double)W2[j];
  for (int off = 32; off; off >>= 1) part += __shfl_xor(part, off);
  int lane = t & 63, w = t >> 6;
  if (lane == 0) red[w] = part;
  __syncthreads();
  if (t == 0) {
    double tot = red[0] + red[1] + red[2] + red[3] + (double)b2[0];
    pv[b] = 1.0 / (1.0 + exp(-tot));
  }
}

// ---------------------------------------------------------------------------
// pack [Wq|Wk] -> transposed [n=1024][k=512] 3-term bf16 split (h/m/l) +
// fp64 bqk. 3-term split captures ~26 mantissa bits of each fp32 weight.
// ---------------------------------------------------------------------------
__global__ __launch_bounds__(256) void pack_wqk3_kernel(
    const float* __restrict__ Wq, const float* __restrict__ Wk,
    const float* __restrict__ bq, const float* __restrict__ bk,
    ushort_t* __restrict__ Wh, ushort_t* __restrict__ Wm,
    ushort_t* __restrict__ Wl, double* __restrict__ bqk) {
  int idx = blockIdx.x * 256 + threadIdx.x;  // 0 .. 1024*512-1
  int n = idx >> 9, k = idx & 511;
  float v = (n < 512) ? Wq[(size_t)k * 512 + n] : Wk[(size_t)k * 512 + (n - 512)];
  ushort_t h = f2bf(v);
  float r1 = v - bf2f(h);
  ushort_t m = f2bf(r1);
  ushort_t l = f2bf(r1 - bf2f(m));
  Wh[idx] = h;
  Wm[idx] = m;
  Wl[idx] = l;
  if (idx < 1024)
    bqk[idx] = (double)((idx < 512) ? bq[idx] : bk[idx - 512]);
}

// ---------------------------------------------------------------------------
// pack W (512x512 fp32, [k][n]) -> WT hi/lo bf16 [n][k] split (value path)
// ---------------------------------------------------------------------------
__global__ __launch_bounds__(256) void pack_wt_kernel(
    const float* __restrict__ W, ushort_t* __restrict__ hiT,
    ushort_t* __restrict__ loT) {
  int i = blockIdx.x * 256 + threadIdx.x;
  int n = i >> 9, k = i & 511;
  float v = W[(size_t)k * 512 + n];
  ushort_t h = f2bf(v);
  hiT[i] = h;
  loT[i] = f2bf(v - bf2f(h));
}

// ---------------------------------------------------------------------------
// q/k projection via 6-segment split-bf16 MFMA with fp64 drain:
// C[M,1024](f64) = A[M,512](f32) @ Wqk + bqk, scores-grade accurate (~6e-8).
// A split on the fly into (h,m,l) bf16; W pre-split transposed [n][k].
// Segments: hH + hM + mH + hL + mM + lH (all terms >= 2^-18).
// fp32 MFMA acc drained into fp64 accumulators every K=64 (bounds fp32
// accumulation error at ~6e-8). 64x64 tile, BK=32, 4 waves 2x2, each wave
// 32x32 via 2x2 of 16x16x32 MFMA. Fragment layout identical to the
// round-5-verified mfma_gemm_split.
// ---------------------------------------------------------------------------
__global__ __launch_bounds__(256) void mfma_qk_split(
    const float* __restrict__ A, const ushort_t* __restrict__ Wh,
    const ushort_t* __restrict__ Wm, const ushort_t* __restrict__ Wl,
    const double* __restrict__ bias, double* __restrict__ C) {
  __shared__ ushort_t As[3][64 * 40];
  __shared__ ushort_t Bs[3][64 * 40];
  int t = threadIdx.x;
  int lane = t & 63, w = t >> 6;
  int wm = w >> 1, wn = w & 1;
  int mrow = lane & 15, quad = lane >> 4;
  int m0 = blockIdx.y * 64, n0 = blockIdx.x * 64;
  floatx4 acc[2][2] = {};
  double dacc[2][2][4] = {};
  for (int kp = 0; kp < 16; ++kp) {
    int k0 = kp * 32;
    __syncthreads();
    {
      int r = t >> 2, c = (t & 3) * 8;
      const float* ap = A + (size_t)(m0 + r) * 512 + k0 + c;
      floatx4 f0 = *(const floatx4*)ap;
      floatx4 f1 = *(const floatx4*)(ap + 4);
      short8 vh, vm, vl;
#pragma unroll
      for (int j = 0; j < 8; ++j) {
        float fv = (j < 4) ? f0[j] : f1[j - 4];
        ushort_t hb = f2bf(fv);
        float r1 = fv - bf2f(hb);
        ushort_t mb = f2bf(r1);
        ushort_t lb = f2bf(r1 - bf2f(mb));
        vh[j] = (short)hb;
        vm[j] = (short)mb;
        vl[j] = (short)lb;
      }
      *(short8*)&As[0][r * 40 + c] = vh;
      *(short8*)&As[1][r * 40 + c] = vm;
      *(short8*)&As[2][r * 40 + c] = vl;
      size_t boff = (size_t)(n0 + r) * 512 + k0 + c;
      *(short8*)&Bs[0][r * 40 + c] = *(const short8*)(Wh + boff);
      *(short8*)&Bs[1][r * 40 + c] = *(const short8*)(Wm + boff);
      *(short8*)&Bs[2][r * 40 + c] = *(const short8*)(Wl + boff);
    }
    __syncthreads();
    short8 aF[2][3], bF[2][3];
#pragma unroll
    for (int i = 0; i < 2; ++i) {
      int ar = (wm * 32 + i * 16 + mrow) * 40 + quad * 8;
      int br = (wn * 32 + i * 16 + mrow) * 40 + quad * 8;
#pragma unroll
      for (int v = 0; v < 3; ++v) {
        aF[i][v] = *(const short8*)&As[v][ar];
        bF[i][v] = *(const short8*)&Bs[v][br];
      }
    }
#pragma unroll
    for (int mt = 0; mt < 2; ++mt)
#pragma unroll
      for (int nt = 0; nt < 2; ++nt) {
        floatx4 a = acc[mt][nt];
        a = __builtin_amdgcn_mfma_f32_16x16x32_bf16(aF[mt][0], bF[nt][0], a, 0, 0, 0);
        a = __builtin_amdgcn_mfma_f32_16x16x32_bf16(aF[mt][0], bF[nt][1], a, 0, 0, 0);
        a = __builtin_amdgcn_mfma_f32_16x16x32_bf16(aF[mt][1], bF[nt][0], a, 0, 0, 0);
        a = __builtin_amdgcn_mfma_f32_16x16x32_bf16(aF[mt][0], bF[nt][2], a, 0, 0, 0);
        a = __builtin_amdgcn_mfma_f32_16x16x32_bf16(aF[mt][1], bF[nt][1], a, 0, 0, 0);
        a = __builtin_amdgcn_mfma_f32_16x16x32_bf16(aF[mt][2], bF[nt][0], a, 0, 0, 0);
        acc[mt][nt] = a;
      }
    if (kp & 1) {  // drain fp32 acc -> fp64 every K=64
#pragma unroll
      for (int mt = 0; mt < 2; ++mt)
#pragma unroll
        for (int nt = 0; nt < 2; ++nt) {
#pragma unroll
          for (int rg = 0; rg < 4; ++rg) dacc[mt][nt][rg] += (double)acc[mt][nt][rg];
          acc[mt][nt] = floatx4{0.f, 0.f, 0.f, 0.f};
        }
    }
  }
#pragma unroll
  for (int nt = 0; nt < 2; ++nt) {
    int gn = n0 + wn * 32 + nt * 16 + mrow;
    double bb = bias[gn];
#pragma unroll
    for (int mt = 0; mt < 2; ++mt) {
      int gm = m0 + wm * 32 + mt * 16 + quad * 4;
#pragma unroll
      for (int rg = 0; rg < 4; ++rg)
        C[(size_t)(gm + rg) * 1024 + gn] = dacc[mt][nt][rg] + bb;
    }
  }
}

// ---------------------------------------------------------------------------
// value-path split-bf16 MFMA GEMM (verified round 5): C = A@(Whi+Wlo)+bias
// ---------------------------------------------------------------------------
__global__ __launch_bounds__(256) void mfma_gemm_split(
    const float* __restrict__ A, const ushort_t* __restrict__ WhiT,
    const ushort_t* __restrict__ WloT, const float* __restrict__ bias,
    float* __restrict__ C) {
  __shared__ ushort_t As[128 * 40];
  __shared__ ushort_t Bs[128 * 40];
  int t = threadIdx.x;
  int lane = t & 63, w = t >> 6;
  int wm = w >> 1, wn = w & 1;
  int mrow = lane & 15, quad = lane >> 4;
  int m0 = blockIdx.y * 128, n0 = blockIdx.x * 128;
  floatx4 acc[4][4] = {};
  for (int kt = 0; kt < 48; ++kt) {
    int seg = kt >> 4;
    int k0 = (kt & 15) * 32;
    const ushort_t* Bseg = (seg == 1) ? WloT : WhiT;
    bool lo = (seg == 2);
    __syncthreads();
#pragma unroll
    for (int p = 0; p < 2; ++p) {
      int idx = p * 256 + t;
      int r = idx >> 2, c = idx & 3;
      const float* ap = A + (size_t)(m0 + r) * 512 + k0 + c * 8;
      floatx4 f0 = *(const floatx4*)ap;
      floatx4 f1 = *(const floatx4*)(ap + 4);
      short8 av;
#pragma unroll
      for (int j = 0; j < 8; ++j) {
        float fv = (j < 4) ? f0[j] : f1[j - 4];
        ushort_t hb = f2bf(fv);
        ushort_t ob = lo ? f2bf(fv - bf2f(hb)) : hb;
        av[j] = (short)ob;
      }
      *(short8*)&As[r * 40 + c * 8] = av;
      *(short8*)&Bs[r * 40 + c * 8] =
          *(const short8*)(Bseg + (size_t)(n0 + r) * 512 + k0 + c * 8);
    }
    __syncthreads();
    short8 af[4], bf8[4];
    int abase = (wm * 64 + mrow) * 40 + quad * 8;
    int bbase = (wn * 64 + mrow) * 40 + quad * 8;
#pragma unroll
    for (int i = 0; i < 4; ++i) {
      af[i] = *(const short8*)&As[abase + i * 640];
      bf8[i] = *(const short8*)&Bs[bbase + i * 640];
    }
#pragma unroll
    for (int mt = 0; mt < 4; ++mt)
#pragma unroll
      for (int nt = 0; nt < 4; ++nt)
        acc[mt][nt] = __builtin_amdgcn_mfma_f32_16x16x32_bf16(
            af[mt], bf8[nt], acc[mt][nt], 0, 0, 0);
  }
#pragma unroll
  for (int nt = 0; nt < 4; ++nt) {
    int gn = n0 + wn * 64 + nt * 16 + mrow;
    float bb = bias[gn];
#pragma unroll
    for (int mt = 0; mt < 4; ++mt) {
      int gm = m0 + wm * 64 + mt * 16 + quad * 4;
#pragma unroll
      for (int rg = 0; rg < 4; ++rg)
        C[(size_t)(gm + rg) * 512 + gn] = acc[mt][nt][rg] + bb;
    }
  }
}

// ---------------------------------------------------------------------------
// attention: fp64 scores; top-64 via 32-round radix select on f32-ordered
// keys + exact u64 refinement inside the tied bucket (rare, wave-uniform).
// Semantics identical to the verified exact select incl. >=thresh ties.
// Soft ramp EPS=2e-6 around (s64+s65)/2; softmax+PV fp32.
// ---------------------------------------------------------------------------
__global__ __launch_bounds__(256) void attn_kernel(
    const double* __restrict__ qk, const float* __restrict__ vbuf,
    const float* __restrict__ corr_prior, const float* __restrict__ feat_imp,
    const double* __restrict__ pv, float* __restrict__ attn_out, int b_off) {
  __shared__ double kT[64][128];  // k[f][d] at kT[d][(f+d)&127]
  int bh = blockIdx.x;
  int b = bh >> 3, h = bh & 7;  // chunk-local b
  int t = threadIdx.x, lane = t & 63, w = t >> 6;
  for (int n = 0; n < 32; ++n) {
    int f = w + 4 * n;
    kT[lane][(f + lane) & 127] =
        qk[((size_t)(b * F_ + f)) * 1024 + 512 + h * 64 + lane];
  }
  __syncthreads();
  double pvb = pv[b_off + b] * 0.5;
  double fiA = (double)feat_imp[lane];
  double fiB = (double)feat_imp[64 + lane];
  const double SLOPE = 2.5e5;  // 1/(2*EPS), EPS = 2e-6
  for (int f = w; f < F_; f += 4) {
    double qreg = qk[((size_t)(b * F_ + f)) * 1024 + h * 64 + lane];
    double s0 = 0.0, s1 = 0.0;
#pragma unroll 8
    for (int d = 0; d < 64; ++d) {
      double qd = bcast64(qreg, d);
      s0 += qd * kT[d][(lane + d) & 127];
      s1 += qd * kT[d][(lane + 64 + d) & 127];
    }
    double fif = (double)feat_imp[f];
    double cp0 = (double)corr_prior[f * 128 + lane] * fif * fiA;
    double cp1 = (double)corr_prior[f * 128 + 64 + lane] * fif * fiB;
    double add0 = (f < 64) ? 0.0 : pvb;
    double add1 = (f < 64) ? pvb : 0.0;
    s0 = s0 * 0.125 + cp0 + add0;
    s1 = s1 * 0.125 + cp1 + add1;
    // stage 1: 32-round select on f32-ordered keys (monotone cast)
    unsigned a0 = f2ord32((float)s0), a1 = f2ord32((float)s1), T = 0u;
    for (int bit = 31; bit >= 0; --bit) {
      unsigned cand = T | (1u << bit);
      int c = __popcll(__ballot(a0 >= cand)) + __popcll(__ballot(a1 >= cand));
      if (c >= KVAL_) T = cand;
    }
    int cnt_gt = __popcll(__ballot(a0 > T)) + __popcll(__ballot(a1 > T));
    int cnt_ge = __popcll(__ballot(a0 >= T)) + __popcll(__ballot(a1 >= T));
    int bsz = cnt_ge - cnt_gt;
    int r = KVAL_ - cnt_gt;  // in-bucket kept count, 1 <= r <= bsz
    double bmax = -1e300;  // max strictly below bucket
    if (a0 < T) bmax = s0;
    if (a1 < T && s1 > bmax) bmax = s1;
    for (int off = 32; off; off >>= 1) bmax = fmax(bmax, __shfl_xor(bmax, off));
    double sT, sU;
    if (bsz == r) {  // common: whole bucket kept; s64 = min-in-bucket
      double tmin = 1e300;
      if (a0 == T) tmin = s0;
      if (a1 == T && s1 < tmin) tmin = s1;
      for (int off = 32; off; off >>= 1) tmin = fmin(tmin, __shfl_xor(tmin, off));
      sT = tmin;
      sU = bmax;
    } else {  // rare: boundary inside f32-tied bucket -> exact u64 refine
      unsigned long long x0 = (a0 == T) ? f2ord64(s0) : 0ull;
      unsigned long long x1 = (a1 == T) ? f2ord64(s1) : 0ull;
      unsigned long long T64 = 0ull;
      for (int bit = 63; bit >= 0; --bit) {
        unsigned long long cand = T64 | (1ull << bit);
        int c = __popcll(__ballot(x0 >= cand)) + __popcll(__ballot(x1 >= cand));
        if (c >= r) T64 = cand;
      }
      double tv = -1e300, uv = bmax;
      if (x0 == T64) tv = s0;
      if (x1 == T64 && s1 > tv) tv = s1;
      if (a0 == T && x0 < T64 && s0 > uv) uv = s0;
      if (a1 == T && x1 < T64 && s1 > uv) uv = s1;
      for (int off = 32; off; off >>= 1) {
        tv = fmax(tv, __shfl_xor(tv, off));
        uv = fmax(uv, __shfl_xor(uv, off));
      }
      sT = tv;
      sU = uv;
    }
    double mid = 0.5 * (sT + sU);
    double W0 = fmin(1.0, fmax(0.0, 0.5 + (s0 - mid) * SLOPE));
    double W1v = fmin(1.0, fmax(0.0, 0.5 + (s1 - mid) * SLOPE));
    double mm = fmax(s0, s1);
    for (int off = 32; off; off >>= 1) mm = fmax(mm, __shfl_xor(mm, off));
    float p0 = (float)W0 * expf((float)(s0 - mm));
    float p1 = (float)W1v * expf((float)(s1 - mm));
    float zz = p0 + p1;
    for (int off = 32; off; off >>= 1) zz += __shfl_xor(zz, off);
    float inv = 1.f / zz;
    const float* vb = vbuf + ((size_t)b * F_) * 512 + h * 64 + lane;
    float o = 0.f;
#pragma unroll 8
    for (int j = 0; j < 64; ++j) o += bcast(p0, j) * vb[(size_t)j * 512];
#pragma unroll 8
    for (int j = 0; j < 64; ++j) o += bcast(p1, j) * vb[(size_t)(j + 64) * 512];
    attn_out[((size_t)(b * F_ + f)) * 512 + h * 64 + lane] = o * inv;
  }
}

extern "C" void kernel_launch(void* const* d_in, const int* in_sizes, int n_in,
                              void* d_out, int out_size, void* d_ws,
                              size_t ws_size, hipStream_t stream) {
  const float* x = (const float*)d_in[0];
  const float* Wq = (const float*)d_in[1];
  const float* bq = (const float*)d_in[2];
  const float* Wk = (const float*)d_in[3];
  const float* bk = (const float*)d_in[4];
  const float* Wv = (const float*)d_in[5];
  const float* bv = (const float*)d_in[6];
  const float* Wo = (const float*)d_in[7];
  const float* bo = (const float*)d_in[8];
  const float* corr = (const float*)d_in[9];
  const float* fimp = (const float*)d_in[10];
  const float* W1 = (const float*)d_in[11];
  const float* b1 = (const float*)d_in[12];
  const float* W2 = (const float*)d_in[13];
  const float* b2 = (const float*)d_in[14];
  float* out = (float*)d_out;
  float* ws = (float*)d_ws;

  // workspace layout (float units):
  //   pv_hi   @0        512       (256 f64)
  //   bqk_hi  @512      2048      (1024 f64)
  //   WqkT_h  @2560     262144    (1024*512 bf16)
  //   WqkT_m  @264704   262144
  //   WqkT_l  @526848   262144
  //   WvhiT   @788992   131072    (512*512 bf16)
  //   WvloT   @920064   131072
  //   WohiT   @1051136  131072
  //   WoloT   @1182208  131072
  //   vbuf    @1313280  16777216  (32768*512 f32)
  //   attnb   @18090496 16777216
  //   qk      @34867712 Bc*262144 (Bc*128*1024 f64, chunk-adaptive)
  double* pv_hi = (double*)ws;
  double* bqk_hi = (double*)(ws + 512);
  ushort_t* WqkTh = (ushort_t*)(ws + 2560);
  ushort_t* WqkTm = (ushort_t*)(ws + 264704);
  ushort_t* WqkTl = (ushort_t*)(ws + 526848);
  ushort_t* WvhiT = (ushort_t*)(ws + 788992);
  ushort_t* WvloT = (ushort_t*)(ws + 920064);
  ushort_t* WohiT = (ushort_t*)(ws + 1051136);
  ushort_t* WoloT = (ushort_t*)(ws + 1182208);
  float* vbuf = ws + 1313280;
  float* attnb = ws + 18090496;
  double* qk = (double*)(ws + 34867712);
  const size_t head = 34867712;
  size_t ws_floats = ws_size / 4;
  int Bc = 8;
  for (int cand = 256; cand >= 8; cand >>= 1)
    if (head + (size_t)cand * 262144 <= ws_floats) { Bc = cand; break; }

  hipLaunchKernelGGL(pv_kernel, dim3(B_), dim3(256), 0, stream,
                     x, W1, b1, W2, b2, pv_hi);
  hipLaunchKernelGGL(pack_wqk3_kernel, dim3(2048), dim3(256), 0, stream,
                     Wq, Wk, bq, bk, WqkTh, WqkTm, WqkTl, bqk_hi);
  hipLaunchKernelGGL(pack_wt_kernel, dim3(1024), dim3(256), 0, stream,
                     Wv, WvhiT, WvloT);
  hipLaunchKernelGGL(pack_wt_kernel, dim3(1024), dim3(256), 0, stream,
                     Wo, WohiT, WoloT);
  // v projection: full batch, M = 32768
  hipLaunchKernelGGL(mfma_gemm_split, dim3(4, 256), dim3(256), 0, stream,
                     x, WvhiT, WvloT, bv, vbuf);
  // selection path, chunked over batch
  for (int b0 = 0; b0 < B_; b0 += Bc) {
    hipLaunchKernelGGL(mfma_qk_split, dim3(16, Bc * 2), dim3(256), 0, stream,
                       x + (size_t)b0 * 65536, WqkTh, WqkTm, WqkTl, bqk_hi, qk);
    hipLaunchKernelGGL(attn_kernel, dim3(Bc * 8), dim3(256), 0, stream,
                       qk, vbuf + (size_t)b0 * 65536, corr, fimp, pv_hi,
                       attnb + (size_t)b0 * 65536, b0);
  }
  // output projection: full batch
  hipLaunchKernelGGL(mfma_gemm_split, dim3(4, 256), dim3(256), 0, stream,
                     attnb, WohiT, WoloT, bo, out);
}

// Round 7
// 1580.701 us; speedup vs baseline: 1.8724x; 1.2507x over previous
//
#include <hip/hip_runtime.h>
#include <hip/hip_bf16.h>
#include <cstdint>

#define B_ 256
#define F_ 128
#define D_ 512
#define H_ 8
#define KVAL_ 64

typedef unsigned short ushort_t;
typedef __attribute__((ext_vector_type(8))) short short8;
typedef __attribute__((ext_vector_type(4))) float floatx4;

__device__ __forceinline__ unsigned f2ord32(float f) {
  unsigned b = __float_as_uint(f);
  return (b & 0x80000000u) ? ~b : (b | 0x80000000u);
}

__device__ __forceinline__ unsigned long long f2ord64(double s) {
  unsigned long long b = (unsigned long long)__double_as_longlong(s);
  return (b & 0x8000000000000000ull) ? ~b : (b | 0x8000000000000000ull);
}

__device__ __forceinline__ float bcast(float v, int l) {
  return __uint_as_float(__builtin_amdgcn_readlane(__float_as_uint(v), l));
}

__device__ __forceinline__ double bcast64(double v, int l) {
  long long x = __double_as_longlong(v);
  unsigned lo = __builtin_amdgcn_readlane((unsigned)(x & 0xffffffffll), l);
  unsigned hi = __builtin_amdgcn_readlane((unsigned)((unsigned long long)x >> 32), l);
  return __longlong_as_double((long long)(((unsigned long long)hi << 32) | lo));
}

__device__ __forceinline__ ushort_t f2bf(float f) {
  __hip_bfloat16 h = __float2bfloat16(f);
  return *reinterpret_cast<ushort_t*>(&h);
}
__device__ __forceinline__ float bf2f(ushort_t u) {
  __hip_bfloat16 h = *reinterpret_cast<__hip_bfloat16*>(&u);
  return __bfloat162float(h);
}

// ---------------------------------------------------------------------------
// pv gate in fp64 (selection-critical): means -> silu MLP -> sigmoid
// ---------------------------------------------------------------------------
__global__ __launch_bounds__(256) void pv_kernel(
    const float* __restrict__ x, const float* __restrict__ W1,
    const float* __restrict__ b1, const float* __restrict__ W2,
    const float* __restrict__ b2, double* __restrict__ pv) {
  __shared__ double comb[1024];
  __shared__ double hbuf[512];
  __shared__ double red[4];
  int b = blockIdx.x, t = threadIdx.x;
  for (int i = t; i < 1024; i += 256) {
    int d = i & 511;
    int fbase = (i < 512) ? 0 : 64;
    const float* xp = x + ((size_t)b * F_ + fbase) * D_ + d;
    double s = 0.0;
#pragma unroll 8
    for (int f = 0; f < 64; ++f) s += (double)xp[(size_t)f * D_];
    comb[i] = s * (1.0 / 64.0);
  }
  __syncthreads();
  for (int j = t; j < 512; j += 256) {
    double acc = (double)b1[j];
#pragma unroll 4
    for (int i = 0; i < 1024; ++i) acc += comb[i] * (double)W1[i * 512 + j];
    hbuf[j] = acc / (1.0 + exp(-acc));  // silu
  }
  __syncthreads();
  double part = 0.0;
  for (int j = t; j < 512; j += 256) part += hbuf[j] * (double)W2[j];
  for (int off = 32; off; off >>= 1) part += __shfl_xor(part, off);
  int lane = t & 63, w = t >> 6;
  if (lane == 0) red[w] = part;
  __syncthreads();
  if (t == 0) {
    double tot = red[0] + red[1] + red[2] + red[3] + (double)b2[0];
    pv[b] = 1.0 / (1.0 + exp(-tot));
  }
}

// ---------------------------------------------------------------------------
// pack [Wq|Wk] -> transposed [n=1024][k=512] 3-term bf16 split (h/m/l) +
// fp64 bqk
// ---------------------------------------------------------------------------
__global__ __launch_bounds__(256) void pack_wqk3_kernel(
    const float* __restrict__ Wq, const float* __restrict__ Wk,
    const float* __restrict__ bq, const float* __restrict__ bk,
    ushort_t* __restrict__ Wh, ushort_t* __restrict__ Wm,
    ushort_t* __restrict__ Wl, double* __restrict__ bqk) {
  int idx = blockIdx.x * 256 + threadIdx.x;  // 0 .. 1024*512-1
  int n = idx >> 9, k = idx & 511;
  float v = (n < 512) ? Wq[(size_t)k * 512 + n] : Wk[(size_t)k * 512 + (n - 512)];
  ushort_t h = f2bf(v);
  float r1 = v - bf2f(h);
  ushort_t m = f2bf(r1);
  ushort_t l = f2bf(r1 - bf2f(m));
  Wh[idx] = h;
  Wm[idx] = m;
  Wl[idx] = l;
  if (idx < 1024)
    bqk[idx] = (double)((idx < 512) ? bq[idx] : bk[idx - 512]);
}

// ---------------------------------------------------------------------------
// pack W (512x512 fp32, [k][n]) -> WT hi/lo bf16 [n][k] split (value path)
// ---------------------------------------------------------------------------
__global__ __launch_bounds__(256) void pack_wt_kernel(
    const float* __restrict__ W, ushort_t* __restrict__ hiT,
    ushort_t* __restrict__ loT) {
  int i = blockIdx.x * 256 + threadIdx.x;
  int n = i >> 9, k = i & 511;
  float v = W[(size_t)k * 512 + n];
  ushort_t h = f2bf(v);
  hiT[i] = h;
  loT[i] = f2bf(v - bf2f(h));
}

// ---------------------------------------------------------------------------
// q/k projection, v2: C[M,1024](f64) = A[M,512](f32) @ Wqk + bqk via
// 6-segment split-bf16 MFMA (terms sa+sb<=2 of A(h/m/l) x W(h/m/l)).
// fp32 MFMA accumulators all the way (error ~1e-7 << EPS=2e-6 ramp), fp64
// bias add in epilogue. 128x128 tile, BK=32, 4 waves 2x2, 4x4 16x16x32 MFMA.
// Segment-pair loop keeps live fragments at 8 short8 (af[4]+bf[4]).
// ---------------------------------------------------------------------------
__global__ __launch_bounds__(256) void mfma_qk_v2(
    const float* __restrict__ A, const ushort_t* __restrict__ Wh,
    const ushort_t* __restrict__ Wm, const ushort_t* __restrict__ Wl,
    const double* __restrict__ bias, double* __restrict__ C) {
  __shared__ ushort_t As[3][128 * 40];
  __shared__ ushort_t Bs[3][128 * 40];
  int t = threadIdx.x;
  int lane = t & 63, w = t >> 6;
  int wm_ = w >> 1, wn = w & 1;
  int mrow = lane & 15, quad = lane >> 4;
  int m0 = blockIdx.y * 128, n0 = blockIdx.x * 128;
  floatx4 acc[4][4] = {};
  const ushort_t* Wseg[3] = {Wh, Wm, Wl};
  for (int kp = 0; kp < 16; ++kp) {
    int k0 = kp * 32;
    __syncthreads();
#pragma unroll
    for (int p = 0; p < 2; ++p) {
      int idx = p * 256 + t;
      int r = idx >> 2, c = (idx & 3) * 8;
      const float* ap = A + (size_t)(m0 + r) * 512 + k0 + c;
      floatx4 f0 = *(const floatx4*)ap;
      floatx4 f1 = *(const floatx4*)(ap + 4);
      short8 vh, vm, vl;
#pragma unroll
      for (int j = 0; j < 8; ++j) {
        float fv = (j < 4) ? f0[j] : f1[j - 4];
        ushort_t hb = f2bf(fv);
        float r1 = fv - bf2f(hb);
        ushort_t mb = f2bf(r1);
        ushort_t lb = f2bf(r1 - bf2f(mb));
        vh[j] = (short)hb;
        vm[j] = (short)mb;
        vl[j] = (short)lb;
      }
      *(short8*)&As[0][r * 40 + c] = vh;
      *(short8*)&As[1][r * 40 + c] = vm;
      *(short8*)&As[2][r * 40 + c] = vl;
      size_t boff = (size_t)(n0 + r) * 512 + k0 + c;
      *(short8*)&Bs[0][r * 40 + c] = *(const short8*)(Wh + boff);
      *(short8*)&Bs[1][r * 40 + c] = *(const short8*)(Wm + boff);
      *(short8*)&Bs[2][r * 40 + c] = *(const short8*)(Wl + boff);
    }
    __syncthreads();
#pragma unroll
    for (int sa = 0; sa < 3; ++sa) {
      short8 af[4];
#pragma unroll
      for (int mt = 0; mt < 4; ++mt)
        af[mt] = *(const short8*)&As[sa][(wm_ * 64 + mt * 16 + mrow) * 40 + quad * 8];
#pragma unroll
      for (int sb = 0; sb < 3; ++sb) {
        if (sa + sb > 2) continue;
        short8 bf[4];
#pragma unroll
        for (int nt = 0; nt < 4; ++nt)
          bf[nt] = *(const short8*)&Bs[sb][(wn * 64 + nt * 16 + mrow) * 40 + quad * 8];
#pragma unroll
        for (int mt = 0; mt < 4; ++mt)
#pragma unroll
          for (int nt = 0; nt < 4; ++nt)
            acc[mt][nt] = __builtin_amdgcn_mfma_f32_16x16x32_bf16(
                af[mt], bf[nt], acc[mt][nt], 0, 0, 0);
      }
    }
  }
#pragma unroll
  for (int nt = 0; nt < 4; ++nt) {
    int gn = n0 + wn * 64 + nt * 16 + mrow;
    double bb = bias[gn];
#pragma unroll
    for (int mt = 0; mt < 4; ++mt) {
      int gm = m0 + wm_ * 64 + mt * 16 + quad * 4;
#pragma unroll
      for (int rg = 0; rg < 4; ++rg)
        C[(size_t)(gm + rg) * 1024 + gn] = (double)acc[mt][nt][rg] + bb;
    }
  }
}

// ---------------------------------------------------------------------------
// value-path split-bf16 MFMA GEMM (verified round 5): C = A@(Whi+Wlo)+bias
// ---------------------------------------------------------------------------
__global__ __launch_bounds__(256) void mfma_gemm_split(
    const float* __restrict__ A, const ushort_t* __restrict__ WhiT,
    const ushort_t* __restrict__ WloT, const float* __restrict__ bias,
    float* __restrict__ C) {
  __shared__ ushort_t As[128 * 40];
  __shared__ ushort_t Bs[128 * 40];
  int t = threadIdx.x;
  int lane = t & 63, w = t >> 6;
  int wm = w >> 1, wn = w & 1;
  int mrow = lane & 15, quad = lane >> 4;
  int m0 = blockIdx.y * 128, n0 = blockIdx.x * 128;
  floatx4 acc[4][4] = {};
  for (int kt = 0; kt < 48; ++kt) {
    int seg = kt >> 4;
    int k0 = (kt & 15) * 32;
    const ushort_t* Bseg = (seg == 1) ? WloT : WhiT;
    bool lo = (seg == 2);
    __syncthreads();
#pragma unroll
    for (int p = 0; p < 2; ++p) {
      int idx = p * 256 + t;
      int r = idx >> 2, c = idx & 3;
      const float* ap = A + (size_t)(m0 + r) * 512 + k0 + c * 8;
      floatx4 f0 = *(const floatx4*)ap;
      floatx4 f1 = *(const floatx4*)(ap + 4);
      short8 av;
#pragma unroll
      for (int j = 0; j < 8; ++j) {
        float fv = (j < 4) ? f0[j] : f1[j - 4];
        ushort_t hb = f2bf(fv);
        ushort_t ob = lo ? f2bf(fv - bf2f(hb)) : hb;
        av[j] = (short)ob;
      }
      *(short8*)&As[r * 40 + c * 8] = av;
      *(short8*)&Bs[r * 40 + c * 8] =
          *(const short8*)(Bseg + (size_t)(n0 + r) * 512 + k0 + c * 8);
    }
    __syncthreads();
    short8 af[4], bf8[4];
    int abase = (wm * 64 + mrow) * 40 + quad * 8;
    int bbase = (wn * 64 + mrow) * 40 + quad * 8;
#pragma unroll
    for (int i = 0; i < 4; ++i) {
      af[i] = *(const short8*)&As[abase + i * 640];
      bf8[i] = *(const short8*)&Bs[bbase + i * 640];
    }
#pragma unroll
    for (int mt = 0; mt < 4; ++mt)
#pragma unroll
      for (int nt = 0; nt < 4; ++nt)
        acc[mt][nt] = __builtin_amdgcn_mfma_f32_16x16x32_bf16(
            af[mt], bf8[nt], acc[mt][nt], 0, 0, 0);
  }
#pragma unroll
  for (int nt = 0; nt < 4; ++nt) {
    int gn = n0 + wn * 64 + nt * 16 + mrow;
    float bb = bias[gn];
#pragma unroll
    for (int mt = 0; mt < 4; ++mt) {
      int gm = m0 + wm * 64 + mt * 16 + quad * 4;
#pragma unroll
      for (int rg = 0; rg < 4; ++rg)
        C[(size_t)(gm + rg) * 512 + gn] = acc[mt][nt][rg] + bb;
    }
  }
}

// ---------------------------------------------------------------------------
// attention v2: same per-row math as the verified round-6 kernel (fp64
// scores, f32-radix select + exact u64 refine, EPS=2e-6 ramp), but each wave
// processes 4 rows per pass: kT LDS reads and v global loads amortize 4x.
// ---------------------------------------------------------------------------
__global__ __launch_bounds__(256) void attn_kernel(
    const double* __restrict__ qk, const float* __restrict__ vbuf,
    const float* __restrict__ corr_prior, const float* __restrict__ feat_imp,
    const double* __restrict__ pv, float* __restrict__ attn_out, int b_off) {
  __shared__ double kT[64][128];  // k[f][d] at kT[d][(f+d)&127]
  int bh = blockIdx.x;
  int b = bh >> 3, h = bh & 7;  // chunk-local b
  int t = threadIdx.x, lane = t & 63, w = t >> 6;
  for (int n = 0; n < 32; ++n) {
    int f = w + 4 * n;
    kT[lane][(f + lane) & 127] =
        qk[((size_t)(b * F_ + f)) * 1024 + 512 + h * 64 + lane];
  }
  __syncthreads();
  double pvb = pv[b_off + b] * 0.5;
  double fiA = (double)feat_imp[lane];
  double fiB = (double)feat_imp[64 + lane];
  const double SLOPE = 2.5e5;  // 1/(2*EPS), EPS = 2e-6
  for (int g = 0; g < 8; ++g) {
    int fb = 16 * g + 4 * w;  // this wave's 4-row group
    double qreg[4], s0[4], s1[4];
#pragma unroll
    for (int i = 0; i < 4; ++i) {
      qreg[i] = qk[((size_t)(b * F_ + fb + i)) * 1024 + h * 64 + lane];
      s0[i] = 0.0;
      s1[i] = 0.0;
    }
#pragma unroll 4
    for (int d = 0; d < 64; ++d) {
      double kd0 = kT[d][(lane + d) & 127];
      double kd1 = kT[d][(lane + 64 + d) & 127];
#pragma unroll
      for (int i = 0; i < 4; ++i) {
        double qd = bcast64(qreg[i], d);
        s0[i] += qd * kd0;
        s1[i] += qd * kd1;
      }
    }
    float p0s[4], p1s[4];
#pragma unroll 1
    for (int i = 0; i < 4; ++i) {
      int f = fb + i;
      double sa = s0[i], sb = s1[i];
      double fif = (double)feat_imp[f];
      double cp0 = (double)corr_prior[f * 128 + lane] * fif * fiA;
      double cp1 = (double)corr_prior[f * 128 + 64 + lane] * fif * fiB;
      double add0 = (f < 64) ? 0.0 : pvb;
      double add1 = (f < 64) ? pvb : 0.0;
      sa = sa * 0.125 + cp0 + add0;
      sb = sb * 0.125 + cp1 + add1;
      // stage 1: 32-round select on f32-ordered keys (monotone cast)
      unsigned a0 = f2ord32((float)sa), a1 = f2ord32((float)sb), T = 0u;
      for (int bit = 31; bit >= 0; --bit) {
        unsigned cand = T | (1u << bit);
        int c = __popcll(__ballot(a0 >= cand)) + __popcll(__ballot(a1 >= cand));
        if (c >= KVAL_) T = cand;
      }
      int cnt_gt = __popcll(__ballot(a0 > T)) + __popcll(__ballot(a1 > T));
      int cnt_ge = __popcll(__ballot(a0 >= T)) + __popcll(__ballot(a1 >= T));
      int bsz = cnt_ge - cnt_gt;
      int r = KVAL_ - cnt_gt;  // in-bucket kept count
      double bmax = -1e300;    // max strictly below bucket
      if (a0 < T) bmax = sa;
      if (a1 < T && sb > bmax) bmax = sb;
      for (int off = 32; off; off >>= 1) bmax = fmax(bmax, __shfl_xor(bmax, off));
      double sT, sU;
      if (bsz == r) {  // common: whole bucket kept
        double tmin = 1e300;
        if (a0 == T) tmin = sa;
        if (a1 == T && sb < tmin) tmin = sb;
        for (int off = 32; off; off >>= 1) tmin = fmin(tmin, __shfl_xor(tmin, off));
        sT = tmin;
        sU = bmax;
      } else {  // rare: exact u64 refine inside tied bucket
        unsigned long long x0 = (a0 == T) ? f2ord64(sa) : 0ull;
        unsigned long long x1 = (a1 == T) ? f2ord64(sb) : 0ull;
        unsigned long long T64 = 0ull;
        for (int bit = 63; bit >= 0; --bit) {
          unsigned long long cand = T64 | (1ull << bit);
          int c = __popcll(__ballot(x0 >= cand)) + __popcll(__ballot(x1 >= cand));
          if (c >= r) T64 = cand;
        }
        double tv = -1e300, uv = bmax;
        if (x0 == T64) tv = sa;
        if (x1 == T64 && sb > tv) tv = sb;
        if (a0 == T && x0 < T64 && sa > uv) uv = sa;
        if (a1 == T && x1 < T64 && sb > uv) uv = sb;
        for (int off = 32; off; off >>= 1) {
          tv = fmax(tv, __shfl_xor(tv, off));
          uv = fmax(uv, __shfl_xor(uv, off));
        }
        sT = tv;
        sU = uv;
      }
      double mid = 0.5 * (sT + sU);
      double W0 = fmin(1.0, fmax(0.0, 0.5 + (sa - mid) * SLOPE));
      double W1v = fmin(1.0, fmax(0.0, 0.5 + (sb - mid) * SLOPE));
      double mm = fmax(sa, sb);
      for (int off = 32; off; off >>= 1) mm = fmax(mm, __shfl_xor(mm, off));
      float p0 = (float)W0 * expf((float)(sa - mm));
      float p1 = (float)W1v * expf((float)(sb - mm));
      float zz = p0 + p1;
      for (int off = 32; off; off >>= 1) zz += __shfl_xor(zz, off);
      float inv = 1.f / zz;
      p0s[i] = p0 * inv;
      p1s[i] = p1 * inv;
    }
    // PV: v loads shared across the 4 rows
    const float* vb = vbuf + ((size_t)b * F_) * 512 + h * 64 + lane;
    float o[4] = {0.f, 0.f, 0.f, 0.f};
#pragma unroll 4
    for (int j = 0; j < 64; ++j) {
      float vj = vb[(size_t)j * 512];
#pragma unroll
      for (int i = 0; i < 4; ++i) o[i] += bcast(p0s[i], j) * vj;
    }
#pragma unroll 4
    for (int j = 0; j < 64; ++j) {
      float vj = vb[(size_t)(j + 64) * 512];
#pragma unroll
      for (int i = 0; i < 4; ++i) o[i] += bcast(p1s[i], j) * vj;
    }
#pragma unroll
    for (int i = 0; i < 4; ++i)
      attn_out[((size_t)(b * F_ + fb + i)) * 512 + h * 64 + lane] = o[i];
  }
}

extern "C" void kernel_launch(void* const* d_in, const int* in_sizes, int n_in,
                              void* d_out, int out_size, void* d_ws,
                              size_t ws_size, hipStream_t stream) {
  const float* x = (const float*)d_in[0];
  const float* Wq = (const float*)d_in[1];
  const float* bq = (const float*)d_in[2];
  const float* Wk = (const float*)d_in[3];
  const float* bk = (const float*)d_in[4];
  const float* Wv = (const float*)d_in[5];
  const float* bv = (const float*)d_in[6];
  const float* Wo = (const float*)d_in[7];
  const float* bo = (const float*)d_in[8];
  const float* corr = (const float*)d_in[9];
  const float* fimp = (const float*)d_in[10];
  const float* W1 = (const float*)d_in[11];
  const float* b1 = (const float*)d_in[12];
  const float* W2 = (const float*)d_in[13];
  const float* b2 = (const float*)d_in[14];
  float* out = (float*)d_out;
  float* ws = (float*)d_ws;

  // workspace layout (float units): same as round 6
  double* pv_hi = (double*)ws;
  double* bqk_hi = (double*)(ws + 512);
  ushort_t* WqkTh = (ushort_t*)(ws + 2560);
  ushort_t* WqkTm = (ushort_t*)(ws + 264704);
  ushort_t* WqkTl = (ushort_t*)(ws + 526848);
  ushort_t* WvhiT = (ushort_t*)(ws + 788992);
  ushort_t* WvloT = (ushort_t*)(ws + 920064);
  ushort_t* WohiT = (ushort_t*)(ws + 1051136);
  ushort_t* WoloT = (ushort_t*)(ws + 1182208);
  float* vbuf = ws + 1313280;
  float* attnb = ws + 18090496;
  double* qk = (double*)(ws + 34867712);
  const size_t head = 34867712;
  size_t ws_floats = ws_size / 4;
  int Bc = 8;
  for (int cand = 256; cand >= 8; cand >>= 1)
    if (head + (size_t)cand * 262144 <= ws_floats) { Bc = cand; break; }

  hipLaunchKernelGGL(pv_kernel, dim3(B_), dim3(256), 0, stream,
                     x, W1, b1, W2, b2, pv_hi);
  hipLaunchKernelGGL(pack_wqk3_kernel, dim3(2048), dim3(256), 0, stream,
                     Wq, Wk, bq, bk, WqkTh, WqkTm, WqkTl, bqk_hi);
  hipLaunchKernelGGL(pack_wt_kernel, dim3(1024), dim3(256), 0, stream,
                     Wv, WvhiT, WvloT);
  hipLaunchKernelGGL(pack_wt_kernel, dim3(1024), dim3(256), 0, stream,
                     Wo, WohiT, WoloT);
  // v projection: full batch, M = 32768
  hipLaunchKernelGGL(mfma_gemm_split, dim3(4, 256), dim3(256), 0, stream,
                     x, WvhiT, WvloT, bv, vbuf);
  // selection path, chunked over batch
  for (int b0 = 0; b0 < B_; b0 += Bc) {
    hipLaunchKernelGGL(mfma_qk_v2, dim3(8, Bc), dim3(256), 0, stream,
                       x + (size_t)b0 * 65536, WqkTh, WqkTm, WqkTl, bqk_hi, qk);
    hipLaunchKernelGGL(attn_kernel, dim3(Bc * 8), dim3(256), 0, stream,
                       qk, vbuf + (size_t)b0 * 65536, corr, fimp, pv_hi,
                       attnb + (size_t)b0 * 65536, b0);
  }
  // output projection: full batch
  hipLaunchKernelGGL(mfma_gemm_split, dim3(4, 256), dim3(256), 0, stream,
                     attnb, WohiT, WoloT, bo, out);
}